// Round 1
// baseline (520.659 us; speedup 1.0000x reference)
//
#include <hip/hip_runtime.h>
#include <cstdint>

typedef unsigned long long u64;

// ---------------------------------------------------------------------------
// Weight sign-packing: wp[(tap*Wi+cw)*Cout + oc], bit i = (w[tap][cw*64+i][oc] > 0)
// ---------------------------------------------------------------------------
__global__ void pack_weights_kernel(const float* __restrict__ w, u64* __restrict__ wp,
                                    int Cin, int Cout) {
    int tid = blockIdx.x * blockDim.x + threadIdx.x;
    int wid = tid >> 6;
    int lane = threadIdx.x & 63;
    int Wi = Cin >> 6;
    int total = 9 * Wi * Cout;
    if (wid >= total) return;
    int oc = wid % Cout;
    int tw = wid / Cout;          // tap*Wi + cw
    int tap = tw / Wi;
    int cw = tw % Wi;
    int ci = cw * 64 + lane;
    float v = w[((size_t)tap * Cin + ci) * Cout + oc];
    u64 mask = __ballot(v > 0.0f);
    if (lane == 0) wp[(size_t)tw * Cout + oc] = mask;
}

// ---------------------------------------------------------------------------
// conv1 (float, 3->128) + b1 + relu + bn1 -> sign bits packed.
// One block = one pixel (128 threads = 128 out channels = 2 waves).
// Double accumulation: sign decisions feed 5 binary layers; must be exact.
// ---------------------------------------------------------------------------
__global__ void conv1_pack_kernel(const float* __restrict__ x, const float* __restrict__ w1,
                                  const float* __restrict__ b1, const float* __restrict__ s1,
                                  const float* __restrict__ bb1, u64* __restrict__ p1) {
    int p = blockIdx.x;            // b*1024 + y*32 + x
    int oc = threadIdx.x;          // 0..127
    int b = p >> 10;
    int y = (p >> 5) & 31;
    int xx = p & 31;
    double acc = 0.0;
    #pragma unroll
    for (int ky = 0; ky < 3; ky++) {
        int iy = y + ky - 1;
        if (iy < 0 || iy > 31) continue;
        #pragma unroll
        for (int kx = 0; kx < 3; kx++) {
            int ix = xx + kx - 1;
            if (ix < 0 || ix > 31) continue;
            const float* xp = x + ((b * 32 + iy) * 32 + ix) * 3;
            const float* wt = w1 + (ky * 3 + kx) * 3 * 128 + oc;
            acc += (double)xp[0] * (double)wt[0];
            acc += (double)xp[1] * (double)wt[128];
            acc += (double)xp[2] * (double)wt[256];
        }
    }
    double v = acc + (double)b1[oc];
    double r = v > 0.0 ? v : 0.0;
    double h = r * (double)s1[oc] + (double)bb1[oc];
    u64 m = __ballot(h > 0.0);
    if ((threadIdx.x & 63) == 0) p1[p * 2 + (threadIdx.x >> 6)] = m;
}

// ---------------------------------------------------------------------------
// Binary conv (+optional 2x2 maxpool) + bn-threshold.
// One wave = one output (pooled) pixel x 64 output channels.
// dot = 2*popcount(XNOR) - nvalid (SAME padding excluded from nvalid).
// BITOUT: __ballot-pack sign bits. Else: write float h (conv6 -> dense).
// ---------------------------------------------------------------------------
template<int WI, int H, int W, int COUT, bool POOL, bool BITOUT>
__global__ __launch_bounds__(256) void bconv_kernel(
        const u64* __restrict__ in, const u64* __restrict__ wp,
        const float* __restrict__ bns, const float* __restrict__ bnb,
        u64* __restrict__ outb, float* __restrict__ outf) {
    constexpr int NP  = POOL ? 4 : 1;
    constexpr int Ho  = POOL ? H / 2 : H;
    constexpr int Wo  = POOL ? W / 2 : W;
    constexpr int WoW = COUT >> 6;
    const int lane = threadIdx.x & 63;
    int wid = (blockIdx.x * blockDim.x + threadIdx.x) >> 6;
    wid = __builtin_amdgcn_readfirstlane(wid);   // force SGPR -> scalar a-loads
    const int wordo = wid % WoW;
    int t = wid / WoW;
    const int ox = t % Wo; t /= Wo;
    const int oy = t % Ho;
    const int b  = t / Ho;
    if (b >= 128) return;
    const int oc = wordo * 64 + lane;

    int m[NP], nv[NP];
    #pragma unroll
    for (int p = 0; p < NP; p++) { m[p] = 0; nv[p] = 0; }

    #pragma unroll
    for (int ky = 0; ky < 3; ky++) {
        #pragma unroll
        for (int kx = 0; kx < 3; kx++) {
            bool vld[NP]; int abase[NP];
            #pragma unroll
            for (int p = 0; p < NP; p++) {
                int py = POOL ? oy * 2 + (p >> 1) : oy;
                int px = POOL ? ox * 2 + (p & 1) : ox;
                int iy = py + ky - 1, ix = px + kx - 1;
                vld[p] = (iy >= 0 && iy < H && ix >= 0 && ix < W);
                abase[p] = ((b * H + iy) * W + ix) * WI;
            }
            const u64* wrow = wp + (ky * 3 + kx) * WI * COUT + oc;
            #pragma unroll
            for (int cw = 0; cw < WI; cw++) {
                u64 wv = wrow[(size_t)cw * COUT];
                #pragma unroll
                for (int p = 0; p < NP; p++) {
                    if (vld[p]) {
                        u64 av = in[abase[p] + cw];
                        m[p] += __popcll(~(av ^ wv));
                        nv[p] += 64;
                    }
                }
            }
        }
    }
    int pmax = 0;   // relu(d) then max over window == max(0, max d)
    #pragma unroll
    for (int p = 0; p < NP; p++) {
        int d = 2 * m[p] - nv[p];
        pmax = d > pmax ? d : pmax;
    }
    double h = (double)pmax * (double)bns[oc] + (double)bnb[oc];
    if constexpr (BITOUT) {
        u64 mask = __ballot(h > 0.0);
        if (lane == 0) outb[((b * Ho + oy) * Wo + ox) * WoW + wordo] = mask;
    } else {
        outf[((b * Ho + oy) * Wo + ox) * COUT + oc] = (float)h;
    }
}

// ---------------------------------------------------------------------------
// Dense (512x10) + softmax. One wave per row (b,y,x). 2048 rows.
// ---------------------------------------------------------------------------
__global__ __launch_bounds__(256) void dense_softmax_kernel(
        const float* __restrict__ h6, const float* __restrict__ dw,
        const float* __restrict__ db, float* __restrict__ out) {
    int lane = threadIdx.x & 63;
    int r = (blockIdx.x * blockDim.x + threadIdx.x) >> 6;
    if (r >= 2048) return;
    const float* hr = h6 + (size_t)r * 512;
    float part[10];
    #pragma unroll
    for (int d = 0; d < 10; d++) part[d] = 0.f;
    #pragma unroll
    for (int k = 0; k < 8; k++) {
        int c = lane + 64 * k;
        float hv = hr[c];
        const float* dwr = dw + c * 10;
        #pragma unroll
        for (int d = 0; d < 10; d++) part[d] += hv * dwr[d];
    }
    #pragma unroll
    for (int off = 32; off >= 1; off >>= 1) {
        #pragma unroll
        for (int d = 0; d < 10; d++) part[d] += __shfl_down(part[d], off, 64);
    }
    if (lane == 0) {
        float logits[10];
        float mx = -1e30f;
        #pragma unroll
        for (int d = 0; d < 10; d++) { logits[d] = part[d] + db[d]; mx = fmaxf(mx, logits[d]); }
        float se = 0.f;
        #pragma unroll
        for (int d = 0; d < 10; d++) { logits[d] = expf(logits[d] - mx); se += logits[d]; }
        float inv = 1.f / se;
        #pragma unroll
        for (int d = 0; d < 10; d++) out[(size_t)r * 10 + d] = logits[d] * inv;
    }
}

// ---------------------------------------------------------------------------
extern "C" void kernel_launch(void* const* d_in, const int* in_sizes, int n_in,
                              void* d_out, int out_size, void* d_ws, size_t ws_size,
                              hipStream_t stream) {
    const float* x    = (const float*)d_in[0];
    const float* w1   = (const float*)d_in[1];
    const float* b1   = (const float*)d_in[2];
    const float* w2   = (const float*)d_in[3];
    const float* w3   = (const float*)d_in[4];
    const float* w4   = (const float*)d_in[5];
    const float* w5   = (const float*)d_in[6];
    const float* w6   = (const float*)d_in[7];
    const float* bn1s = (const float*)d_in[8];
    const float* bn1b = (const float*)d_in[9];
    const float* bn2s = (const float*)d_in[10];
    const float* bn2b = (const float*)d_in[11];
    const float* bn3s = (const float*)d_in[12];
    const float* bn3b = (const float*)d_in[13];
    const float* bn4s = (const float*)d_in[14];
    const float* bn4b = (const float*)d_in[15];
    const float* bn5s = (const float*)d_in[16];
    const float* bn5b = (const float*)d_in[17];
    const float* bn6s = (const float*)d_in[18];
    const float* bn6b = (const float*)d_in[19];
    const float* dw   = (const float*)d_in[20];
    const float* db   = (const float*)d_in[21];
    float* out = (float*)d_out;

    // workspace layout (u64 units)
    u64* ws  = (u64*)d_ws;
    u64* wp2 = ws;              // 9*2*128  = 2304
    u64* wp3 = wp2 + 2304;      // 9*2*256  = 4608
    u64* wp4 = wp3 + 4608;      // 9*4*256  = 9216
    u64* wp5 = wp4 + 9216;      // 9*4*512  = 18432
    u64* wp6 = wp5 + 18432;     // 9*8*512  = 36864
    u64* p1  = wp6 + 36864;     // 128*32*32*2 = 262144
    u64* p2  = p1 + 262144;     // 128*16*16*2 = 65536
    u64* p3  = p2 + 65536;      // 128*16*16*4 = 131072
    u64* p4  = p3 + 131072;     // 128*8*8*4   = 32768
    u64* p5  = p4 + 32768;      // 128*8*8*8   = 65536
    float* h6 = (float*)(p5 + 65536);  // 128*4*4*512 floats = 4 MB

    // pack binary weights (sign bits)
    pack_weights_kernel<<<(9*2*128*64)/256, 256, 0, stream>>>(w2, wp2, 128, 128);
    pack_weights_kernel<<<(9*2*256*64)/256, 256, 0, stream>>>(w3, wp3, 128, 256);
    pack_weights_kernel<<<(9*4*256*64)/256, 256, 0, stream>>>(w4, wp4, 256, 256);
    pack_weights_kernel<<<(9*4*512*64)/256, 256, 0, stream>>>(w5, wp5, 256, 512);
    pack_weights_kernel<<<(9*8*512*64)/256, 256, 0, stream>>>(w6, wp6, 512, 512);

    // conv1 + bn1 -> p1
    conv1_pack_kernel<<<128*32*32, 128, 0, stream>>>(x, w1, b1, bn1s, bn1b, p1);

    // conv2 (binary, pool) -> p2 : 128x16x16 x 2 words = 65536 waves
    bconv_kernel<2,32,32,128,true, true><<<65536*64/256, 256, 0, stream>>>(p1, wp2, bn2s, bn2b, p2, nullptr);
    // conv3 (binary) -> p3 : 128*16*16*4 = 131072 waves
    bconv_kernel<2,16,16,256,false,true><<<131072*64/256, 256, 0, stream>>>(p2, wp3, bn3s, bn3b, p3, nullptr);
    // conv4 (binary, pool) -> p4 : 128*8*8*4 = 32768 waves
    bconv_kernel<4,16,16,256,true, true><<<32768*64/256, 256, 0, stream>>>(p3, wp4, bn4s, bn4b, p4, nullptr);
    // conv5 (binary) -> p5 : 128*8*8*8 = 65536 waves
    bconv_kernel<4,8,8,512,false,true><<<65536*64/256, 256, 0, stream>>>(p4, wp5, bn5s, bn5b, p5, nullptr);
    // conv6 (binary, pool, float out) -> h6 : 128*4*4*8 = 16384 waves
    bconv_kernel<8,8,8,512,true, false><<<16384*64/256, 256, 0, stream>>>(p5, wp6, bn6s, bn6b, nullptr, h6);

    // dense + softmax : 2048 rows, one wave each
    dense_softmax_kernel<<<2048*64/256, 256, 0, stream>>>(h6, dw, db, out);
}

// Round 2
// 442.089 us; speedup vs baseline: 1.1777x; 1.1777x over previous
//
#include <hip/hip_runtime.h>
#include <cstdint>

typedef unsigned long long u64;

// ---------------------------------------------------------------------------
// Weight sign-packing: wp[(tap*Wi+cw)*Cout + oc], bit i = (w[tap][cw*64+i][oc] > 0)
// ---------------------------------------------------------------------------
__global__ void pack_weights_kernel(const float* __restrict__ w, u64* __restrict__ wp,
                                    int Cin, int Cout) {
    int tid = blockIdx.x * blockDim.x + threadIdx.x;
    int wid = tid >> 6;
    int lane = threadIdx.x & 63;
    int Wi = Cin >> 6;
    int total = 9 * Wi * Cout;
    if (wid >= total) return;
    int oc = wid % Cout;
    int tw = wid / Cout;          // tap*Wi + cw
    int tap = tw / Wi;
    int cw = tw % Wi;
    int ci = cw * 64 + lane;
    float v = w[((size_t)tap * Cin + ci) * Cout + oc];
    u64 mask = __ballot(v > 0.0f);
    if (lane == 0) wp[(size_t)tw * Cout + oc] = mask;
}

// ---------------------------------------------------------------------------
// conv1 (float, 3->128) + b1 + relu + bn1 -> sign bits packed.
// Block = 128 threads (= 128 out channels, 2 waves) handling 8 pixels of one
// row. Weights held in VGPRs (27 doubles); x loads are wave-uniform scalars;
// input-centric sliding window: each x value feeds 3 output accumulators.
// Double accumulation: sign decisions feed 5 binary layers; must be exact.
// ---------------------------------------------------------------------------
__global__ __launch_bounds__(128) void conv1_pack_kernel(
        const float* __restrict__ x, const float* __restrict__ w1,
        const float* __restrict__ b1, const float* __restrict__ s1,
        const float* __restrict__ bb1, u64* __restrict__ p1) {
    const int t = threadIdx.x;
    const int oc = t;
    const int bx = blockIdx.x;
    const int xseg = (bx & 3) << 3;    // 0,8,16,24
    const int y = (bx >> 2) & 31;
    const int b = bx >> 7;

    double wreg[27];
    #pragma unroll
    for (int k = 0; k < 27; k++) wreg[k] = (double)w1[k * 128 + oc];
    const double b1v = (double)b1[oc];
    // h = relu(acc+b1)*s + bb > 0  <=>  (bb>0) || acc > -bb/s - b1   (s>0)
    const double tneg = -(double)bb1[oc] / (double)s1[oc];
    const bool always = tneg < 0.0;
    const double thr = tneg - b1v;

    double acc[8];
    #pragma unroll
    for (int i = 0; i < 8; i++) acc[i] = 0.0;

    #pragma unroll
    for (int ky = 0; ky < 3; ky++) {
        int iy = y - 1 + ky;
        if (iy < 0 || iy > 31) continue;
        #pragma unroll
        for (int col = 0; col < 10; col++) {
            int ix = xseg - 1 + col;
            if (ix < 0 || ix > 31) continue;
            const float* xp = x + ((b * 32 + iy) * 32 + ix) * 3;
            #pragma unroll
            for (int c = 0; c < 3; c++) {
                double xv = (double)xp[c];
                #pragma unroll
                for (int kx = 0; kx < 3; kx++) {
                    int px = col - kx;          // output pixel this tap feeds
                    if (px >= 0 && px < 8)
                        acc[px] += xv * wreg[(ky * 3 + kx) * 3 + c];
                }
            }
        }
    }
    #pragma unroll
    for (int px = 0; px < 8; px++) {
        bool bit = always || (acc[px] > thr);
        u64 m = __ballot(bit);
        if ((t & 63) == 0)
            p1[((((b * 32 + y) * 32) + xseg + px) << 1) + (t >> 6)] = m;
    }
}

// ---------------------------------------------------------------------------
// Binary conv (+optional 2x2 maxpool) + bn-threshold.
// One wave = POUT output pixels (along x) x 64 output channels; each weight
// word load amortizes over POUT x NPW popcount units. a-loads are
// wave-uniform (scalar). dot = 2*popcount(XNOR) - nvalid, nvalid computed
// analytically in the epilogue (SAME padding excludes OOB taps).
// ---------------------------------------------------------------------------
template<int WI, int H, int W, int COUT, bool POOL, int POUT, bool BITOUT>
__global__ __launch_bounds__(256) void bconv_kernel(
        const u64* __restrict__ in, const u64* __restrict__ wp,
        const float* __restrict__ bns, const float* __restrict__ bnb,
        u64* __restrict__ outb, float* __restrict__ outf) {
    constexpr int NPW = POOL ? 4 : 1;     // window pixels per output
    constexpr int Ho  = POOL ? H / 2 : H;
    constexpr int Wo  = POOL ? W / 2 : W;
    constexpr int WoW = COUT >> 6;
    constexpr int NG  = Wo / POUT;        // pixel-groups per row
    const int lane = threadIdx.x & 63;
    int wid = (blockIdx.x * blockDim.x + threadIdx.x) >> 6;
    wid = __builtin_amdgcn_readfirstlane(wid);   // force SGPR -> scalar a-loads
    const int wordo = wid % WoW;
    int t = wid / WoW;
    const int og = (t % NG) * POUT; t /= NG;
    const int oy = t % Ho;
    const int b  = t / Ho;
    if (b >= 128) return;
    const int oc = wordo * 64 + lane;

    int m[POUT][NPW];
    #pragma unroll
    for (int po = 0; po < POUT; po++)
        #pragma unroll
        for (int w = 0; w < NPW; w++) m[po][w] = 0;

    #pragma unroll
    for (int ky = 0; ky < 3; ky++) {
        #pragma unroll
        for (int kx = 0; kx < 3; kx++) {
            const u64* wrow = wp + (size_t)((ky * 3 + kx) * WI) * COUT + oc;
            #pragma unroll
            for (int cw = 0; cw < WI; cw++) {
                u64 wv = wrow[(size_t)cw * COUT];
                #pragma unroll
                for (int po = 0; po < POUT; po++) {
                    #pragma unroll
                    for (int w = 0; w < NPW; w++) {
                        const int wy = POOL ? (w >> 1) : 0;
                        const int wx = POOL ? (w & 1) : 0;
                        int py = POOL ? oy * 2 + wy : oy;
                        int px = POOL ? (og + po) * 2 + wx : og + po;
                        int iy = py + ky - 1, ix = px + kx - 1;
                        if (iy >= 0 && iy < H && ix >= 0 && ix < W) {
                            u64 av = in[((size_t)(b * H + iy) * W + ix) * WI + cw];
                            m[po][w] += __popcll(~(av ^ wv));
                        }
                    }
                }
            }
        }
    }
    #pragma unroll
    for (int po = 0; po < POUT; po++) {
        int pmax = 0;   // relu then max over window == max(0, max d)
        #pragma unroll
        for (int w = 0; w < NPW; w++) {
            const int wy = POOL ? (w >> 1) : 0;
            const int wx = POOL ? (w & 1) : 0;
            int py = POOL ? oy * 2 + wy : oy;
            int px = POOL ? (og + po) * 2 + wx : og + po;
            int nty = 3 - (py == 0) - (py == H - 1);
            int ntx = 3 - (px == 0) - (px == W - 1);
            int d = 2 * m[po][w] - 64 * WI * nty * ntx;
            pmax = d > pmax ? d : pmax;
        }
        double h = (double)pmax * (double)bns[oc] + (double)bnb[oc];
        if constexpr (BITOUT) {
            u64 mask = __ballot(h > 0.0);
            if (lane == 0)
                outb[((size_t)(b * Ho + oy) * Wo + og + po) * WoW + wordo] = mask;
        } else {
            outf[((size_t)(b * Ho + oy) * Wo + og + po) * COUT + oc] = (float)h;
        }
    }
}

// ---------------------------------------------------------------------------
// Dense (512x10) + softmax. One wave per row (b,y,x). 2048 rows.
// ---------------------------------------------------------------------------
__global__ __launch_bounds__(256) void dense_softmax_kernel(
        const float* __restrict__ h6, const float* __restrict__ dw,
        const float* __restrict__ db, float* __restrict__ out) {
    int lane = threadIdx.x & 63;
    int r = (blockIdx.x * blockDim.x + threadIdx.x) >> 6;
    if (r >= 2048) return;
    const float* hr = h6 + (size_t)r * 512;
    float part[10];
    #pragma unroll
    for (int d = 0; d < 10; d++) part[d] = 0.f;
    #pragma unroll
    for (int k = 0; k < 8; k++) {
        int c = lane + 64 * k;
        float hv = hr[c];
        const float* dwr = dw + c * 10;
        #pragma unroll
        for (int d = 0; d < 10; d++) part[d] += hv * dwr[d];
    }
    #pragma unroll
    for (int off = 32; off >= 1; off >>= 1) {
        #pragma unroll
        for (int d = 0; d < 10; d++) part[d] += __shfl_down(part[d], off, 64);
    }
    if (lane == 0) {
        float logits[10];
        float mx = -1e30f;
        #pragma unroll
        for (int d = 0; d < 10; d++) { logits[d] = part[d] + db[d]; mx = fmaxf(mx, logits[d]); }
        float se = 0.f;
        #pragma unroll
        for (int d = 0; d < 10; d++) { logits[d] = expf(logits[d] - mx); se += logits[d]; }
        float inv = 1.f / se;
        #pragma unroll
        for (int d = 0; d < 10; d++) out[(size_t)r * 10 + d] = logits[d] * inv;
    }
}

// ---------------------------------------------------------------------------
extern "C" void kernel_launch(void* const* d_in, const int* in_sizes, int n_in,
                              void* d_out, int out_size, void* d_ws, size_t ws_size,
                              hipStream_t stream) {
    const float* x    = (const float*)d_in[0];
    const float* w1   = (const float*)d_in[1];
    const float* b1   = (const float*)d_in[2];
    const float* w2   = (const float*)d_in[3];
    const float* w3   = (const float*)d_in[4];
    const float* w4   = (const float*)d_in[5];
    const float* w5   = (const float*)d_in[6];
    const float* w6   = (const float*)d_in[7];
    const float* bn1s = (const float*)d_in[8];
    const float* bn1b = (const float*)d_in[9];
    const float* bn2s = (const float*)d_in[10];
    const float* bn2b = (const float*)d_in[11];
    const float* bn3s = (const float*)d_in[12];
    const float* bn3b = (const float*)d_in[13];
    const float* bn4s = (const float*)d_in[14];
    const float* bn4b = (const float*)d_in[15];
    const float* bn5s = (const float*)d_in[16];
    const float* bn5b = (const float*)d_in[17];
    const float* bn6s = (const float*)d_in[18];
    const float* bn6b = (const float*)d_in[19];
    const float* dw   = (const float*)d_in[20];
    const float* db   = (const float*)d_in[21];
    float* out = (float*)d_out;

    // workspace layout (u64 units)
    u64* ws  = (u64*)d_ws;
    u64* wp2 = ws;              // 9*2*128  = 2304
    u64* wp3 = wp2 + 2304;      // 9*2*256  = 4608
    u64* wp4 = wp3 + 4608;      // 9*4*256  = 9216
    u64* wp5 = wp4 + 9216;      // 9*4*512  = 18432
    u64* wp6 = wp5 + 18432;     // 9*8*512  = 36864
    u64* p1  = wp6 + 36864;     // 128*32*32*2 = 262144
    u64* p2  = p1 + 262144;     // 128*16*16*2 = 65536
    u64* p3  = p2 + 65536;      // 128*16*16*4 = 131072
    u64* p4  = p3 + 131072;     // 128*8*8*4   = 32768
    u64* p5  = p4 + 32768;      // 128*8*8*8   = 65536
    float* h6 = (float*)(p5 + 65536);  // 128*4*4*512 floats = 4 MB

    // pack binary weights (sign bits)
    pack_weights_kernel<<<(9*2*128*64)/256, 256, 0, stream>>>(w2, wp2, 128, 128);
    pack_weights_kernel<<<(9*2*256*64)/256, 256, 0, stream>>>(w3, wp3, 128, 256);
    pack_weights_kernel<<<(9*4*256*64)/256, 256, 0, stream>>>(w4, wp4, 256, 256);
    pack_weights_kernel<<<(9*4*512*64)/256, 256, 0, stream>>>(w5, wp5, 256, 512);
    pack_weights_kernel<<<(9*8*512*64)/256, 256, 0, stream>>>(w6, wp6, 512, 512);

    // conv1 + bn1 -> p1 : 128*32*4 blocks of 128 threads (8 px/thread)
    conv1_pack_kernel<<<128*32*4, 128, 0, stream>>>(x, w1, b1, bn1s, bn1b, p1);

    // conv2 (binary, pool) -> p2 : 16384 waves
    bconv_kernel<2,32,32,128,true, 4,true><<<4096, 256, 0, stream>>>(p1, wp2, bn2s, bn2b, p2, nullptr);
    // conv3 (binary) -> p3 : 16384 waves
    bconv_kernel<2,16,16,256,false,8,true><<<4096, 256, 0, stream>>>(p2, wp3, bn3s, bn3b, p3, nullptr);
    // conv4 (binary, pool) -> p4 : 8192 waves
    bconv_kernel<4,16,16,256,true, 4,true><<<2048, 256, 0, stream>>>(p3, wp4, bn4s, bn4b, p4, nullptr);
    // conv5 (binary) -> p5 : 8192 waves
    bconv_kernel<4,8,8,512,false,8,true><<<2048, 256, 0, stream>>>(p4, wp5, bn5s, bn5b, p5, nullptr);
    // conv6 (binary, pool, float out) -> h6 : 4096 waves
    bconv_kernel<8,8,8,512,true, 4,false><<<1024, 256, 0, stream>>>(p5, wp6, bn6s, bn6b, nullptr, h6);

    // dense + softmax : 2048 rows, one wave each
    dense_softmax_kernel<<<2048*64/256, 256, 0, stream>>>(h6, dw, db, out);
}

// Round 3
// 376.790 us; speedup vs baseline: 1.3818x; 1.1733x over previous
//
#include <hip/hip_runtime.h>
#include <cstdint>

typedef unsigned long long u64;

// ---------------------------------------------------------------------------
// Zero a u64 region (padded bit-map halos must be 0; ws is poisoned 0xAA).
// ---------------------------------------------------------------------------
__global__ void zero_kernel(u64* __restrict__ p, int n) {
    int i = blockIdx.x * blockDim.x + threadIdx.x;
    int stride = gridDim.x * blockDim.x;
    for (; i < n; i += stride) p[i] = 0;
}

// ---------------------------------------------------------------------------
// Weight sign-packing: wp[(tap*Wi+cw)*Cout + oc], bit i = (w[tap][cw*64+i][oc] > 0)
// ---------------------------------------------------------------------------
__global__ void pack_weights_kernel(const float* __restrict__ w, u64* __restrict__ wp,
                                    int Cin, int Cout) {
    int tid = blockIdx.x * blockDim.x + threadIdx.x;
    int wid = tid >> 6;
    int lane = threadIdx.x & 63;
    int Wi = Cin >> 6;
    int total = 9 * Wi * Cout;
    if (wid >= total) return;
    int oc = wid % Cout;
    int tw = wid / Cout;          // tap*Wi + cw
    int tap = tw / Wi;
    int cw = tw % Wi;
    int ci = cw * 64 + lane;
    float v = w[((size_t)tap * Cin + ci) * Cout + oc];
    u64 mask = __ballot(v > 0.0f);
    if (lane == 0) wp[(size_t)tw * Cout + oc] = mask;
}

// ---------------------------------------------------------------------------
// conv1 (float, 3->128) + b1 + relu + bn1 -> sign bits, written into the
// PADDED 34x34x2-word p1 map. Weights in VGPRs, 8 px/thread sliding window.
// Double accumulation: sign decisions feed 5 binary layers; must be exact.
// ---------------------------------------------------------------------------
__global__ __launch_bounds__(128) void conv1_pack_kernel(
        const float* __restrict__ x, const float* __restrict__ w1,
        const float* __restrict__ b1, const float* __restrict__ s1,
        const float* __restrict__ bb1, u64* __restrict__ p1) {
    const int t = threadIdx.x;
    const int oc = t;
    const int bx = blockIdx.x;
    const int xseg = (bx & 3) << 3;    // 0,8,16,24
    const int y = (bx >> 2) & 31;
    const int b = bx >> 7;

    double wreg[27];
    #pragma unroll
    for (int k = 0; k < 27; k++) wreg[k] = (double)w1[k * 128 + oc];
    const double b1v = (double)b1[oc];
    // h = relu(acc+b1)*s + bb > 0  <=>  (bb>0) || acc > -bb/s - b1   (s>0)
    const double tneg = -(double)bb1[oc] / (double)s1[oc];
    const bool always = tneg < 0.0;
    const double thr = tneg - b1v;

    double acc[8];
    #pragma unroll
    for (int i = 0; i < 8; i++) acc[i] = 0.0;

    #pragma unroll
    for (int ky = 0; ky < 3; ky++) {
        int iy = y - 1 + ky;
        if (iy < 0 || iy > 31) continue;
        #pragma unroll
        for (int col = 0; col < 10; col++) {
            int ix = xseg - 1 + col;
            if (ix < 0 || ix > 31) continue;
            const float* xp = x + ((b * 32 + iy) * 32 + ix) * 3;
            #pragma unroll
            for (int c = 0; c < 3; c++) {
                double xv = (double)xp[c];
                #pragma unroll
                for (int kx = 0; kx < 3; kx++) {
                    int px = col - kx;          // output pixel this tap feeds
                    if (px >= 0 && px < 8)
                        acc[px] += xv * wreg[(ky * 3 + kx) * 3 + c];
                }
            }
        }
    }
    #pragma unroll
    for (int px = 0; px < 8; px++) {
        bool bit = always || (acc[px] > thr);
        u64 m = __ballot(bit);
        if ((t & 63) == 0)
            p1[((size_t)(b * 34 + y + 1) * 34 + xseg + px + 1) * 2 + (t >> 6)] = m;
    }
}

// ---------------------------------------------------------------------------
// Binary conv v2: zero-padded input maps, weights held in VGPRs, one wave =
// one full output row x 64 output channels. Input-centric sweep: each
// wave-uniform activation word (scalar load) feeds 3 kx-taps x ROWS rows of
// register accumulators. SAME-padding handled by exact integer correction:
//   d = 2*m_total + 2*S_oob - 64*WI*(9 + n_oob)
// where S_oob sums per-tap weight popcounts over OOB taps.
// ---------------------------------------------------------------------------
template<int WI, int H, int W, int COUT, bool POOL, bool BITOUT>
__global__ __launch_bounds__(256) void bconv2_kernel(
        const u64* __restrict__ in, const u64* __restrict__ wp,
        const float* __restrict__ bns, const float* __restrict__ bnb,
        u64* __restrict__ outb, float* __restrict__ outf) {
    constexpr int ROWS = POOL ? 2 : 1;      // pre-pool rows per wave
    constexpr int NIR  = ROWS + 2;          // padded input rows touched
    constexpr int Ho   = POOL ? H / 2 : H;
    constexpr int Wo   = POOL ? W / 2 : W;
    constexpr int WoW  = COUT >> 6;
    constexpr int Hp   = H + 2, Wp = W + 2;
    const int lane = threadIdx.x & 63;
    int wid = (blockIdx.x * blockDim.x + threadIdx.x) >> 6;
    wid = __builtin_amdgcn_readfirstlane(wid);   // SGPR -> scalar a-loads
    const int wordo = wid % WoW;
    int t = wid / WoW;
    const int oy = t % Ho;
    const int b  = t / Ho;
    if (b >= 128) return;
    const int oc = wordo * 64 + lane;

    // ---- weights into VGPRs (once per wave) ----
    u64 wreg[9][WI];
    #pragma unroll
    for (int t9 = 0; t9 < 9; t9++)
        #pragma unroll
        for (int cw = 0; cw < WI; cw++)
            wreg[t9][cw] = wp[(size_t)(t9 * WI + cw) * COUT + oc];

    int pcwt[9];                             // per-tap weight popcounts
    #pragma unroll
    for (int t9 = 0; t9 < 9; t9++) {
        int s = 0;
        #pragma unroll
        for (int cw = 0; cw < WI; cw++) s += (int)__popcll(wreg[t9][cw]);
        pcwt[t9] = s;
    }

    int m[ROWS][W];
    #pragma unroll
    for (int r = 0; r < ROWS; r++)
        #pragma unroll
        for (int c = 0; c < W; c++) m[r][c] = 0;

    const int base = POOL ? oy * 2 : oy;     // first pre-pool row (unpadded)
    const u64* inb = in + ((size_t)b * Hp + base) * Wp * WI;

    #pragma unroll
    for (int ir = 0; ir < NIR; ir++) {       // padded input row = base + ir
        const u64* inrow = inb + (size_t)ir * Wp * WI;
        #pragma unroll
        for (int c = 0; c < Wp; c++) {       // padded input col
            u64 av[WI];
            #pragma unroll
            for (int cw = 0; cw < WI; cw++) av[cw] = inrow[c * WI + cw];
            #pragma unroll
            for (int r = 0; r < ROWS; r++) {
                const int ky = ir - r;
                if (ky < 0 || ky > 2) continue;
                #pragma unroll
                for (int kx = 0; kx < 3; kx++) {
                    const int col = c - kx;  // output col fed by this tap
                    if (col < 0 || col >= W) continue;
                    int acc = 0;
                    #pragma unroll
                    for (int cw = 0; cw < WI; cw++)
                        acc += (int)__popcll(~(av[cw] ^ wreg[ky * 3 + kx][cw]));
                    m[r][col] += acc;
                }
            }
        }
    }

    // ---- epilogue: padding correction, relu+pool max, threshold ----
    const double sc = (double)bns[oc];
    const double bi = (double)bnb[oc];
    const double tf = -bi / sc;              // bit = pmax > tf  (sc > 0)

    #pragma unroll
    for (int po = 0; po < Wo; po++) {
        int pmax = 0;                        // relu then max == max(0, d...)
        #pragma unroll
        for (int r = 0; r < ROWS; r++) {
            #pragma unroll
            for (int wx = 0; wx < (POOL ? 2 : 1); wx++) {
                const int pc = POOL ? po * 2 + wx : po;   // compile-time col
                const int pr = base + r;                  // uniform row
                const bool top = (pr == 0), bot = (pr == H - 1);
                const bool lef = (pc == 0), rig = (pc == W - 1);
                int n_oob = 0, S = 0;
                if (top) { n_oob += 3; S += pcwt[0] + pcwt[1] + pcwt[2]; }
                if (bot) { n_oob += 3; S += pcwt[6] + pcwt[7] + pcwt[8]; }
                if (lef) { n_oob += 3; S += pcwt[0] + pcwt[3] + pcwt[6]; }
                if (rig) { n_oob += 3; S += pcwt[2] + pcwt[5] + pcwt[8]; }
                if (top && lef) { n_oob -= 1; S -= pcwt[0]; }
                if (top && rig) { n_oob -= 1; S -= pcwt[2]; }
                if (bot && lef) { n_oob -= 1; S -= pcwt[6]; }
                if (bot && rig) { n_oob -= 1; S -= pcwt[8]; }
                int d = 2 * m[r][pc] + 2 * S - 64 * WI * (9 + n_oob);
                pmax = d > pmax ? d : pmax;
            }
        }
        if constexpr (BITOUT) {
            u64 mask = __ballot((double)pmax > tf);
            if (lane == 0)
                outb[((size_t)(b * (Ho + 2) + oy + 1) * (Wo + 2) + po + 1) * WoW + wordo] = mask;
        } else {
            double h = (double)pmax * sc + bi;
            outf[((size_t)(b * Ho + oy) * Wo + po) * COUT + oc] = (float)h;
        }
    }
}

// ---------------------------------------------------------------------------
// Dense (512x10) + softmax. One wave per row (b,y,x). 2048 rows.
// ---------------------------------------------------------------------------
__global__ __launch_bounds__(256) void dense_softmax_kernel(
        const float* __restrict__ h6, const float* __restrict__ dw,
        const float* __restrict__ db, float* __restrict__ out) {
    int lane = threadIdx.x & 63;
    int r = (blockIdx.x * blockDim.x + threadIdx.x) >> 6;
    if (r >= 2048) return;
    const float* hr = h6 + (size_t)r * 512;
    float part[10];
    #pragma unroll
    for (int d = 0; d < 10; d++) part[d] = 0.f;
    #pragma unroll
    for (int k = 0; k < 8; k++) {
        int c = lane + 64 * k;
        float hv = hr[c];
        const float* dwr = dw + c * 10;
        #pragma unroll
        for (int d = 0; d < 10; d++) part[d] += hv * dwr[d];
    }
    #pragma unroll
    for (int off = 32; off >= 1; off >>= 1) {
        #pragma unroll
        for (int d = 0; d < 10; d++) part[d] += __shfl_down(part[d], off, 64);
    }
    if (lane == 0) {
        float logits[10];
        float mx = -1e30f;
        #pragma unroll
        for (int d = 0; d < 10; d++) { logits[d] = part[d] + db[d]; mx = fmaxf(mx, logits[d]); }
        float se = 0.f;
        #pragma unroll
        for (int d = 0; d < 10; d++) { logits[d] = expf(logits[d] - mx); se += logits[d]; }
        float inv = 1.f / se;
        #pragma unroll
        for (int d = 0; d < 10; d++) out[(size_t)r * 10 + d] = logits[d] * inv;
    }
}

// ---------------------------------------------------------------------------
extern "C" void kernel_launch(void* const* d_in, const int* in_sizes, int n_in,
                              void* d_out, int out_size, void* d_ws, size_t ws_size,
                              hipStream_t stream) {
    const float* x    = (const float*)d_in[0];
    const float* w1   = (const float*)d_in[1];
    const float* b1   = (const float*)d_in[2];
    const float* w2   = (const float*)d_in[3];
    const float* w3   = (const float*)d_in[4];
    const float* w4   = (const float*)d_in[5];
    const float* w5   = (const float*)d_in[6];
    const float* w6   = (const float*)d_in[7];
    const float* bn1s = (const float*)d_in[8];
    const float* bn1b = (const float*)d_in[9];
    const float* bn2s = (const float*)d_in[10];
    const float* bn2b = (const float*)d_in[11];
    const float* bn3s = (const float*)d_in[12];
    const float* bn3b = (const float*)d_in[13];
    const float* bn4s = (const float*)d_in[14];
    const float* bn4b = (const float*)d_in[15];
    const float* bn5s = (const float*)d_in[16];
    const float* bn5b = (const float*)d_in[17];
    const float* bn6s = (const float*)d_in[18];
    const float* bn6b = (const float*)d_in[19];
    const float* dw   = (const float*)d_in[20];
    const float* db   = (const float*)d_in[21];
    float* out = (float*)d_out;

    // workspace layout (u64 units); p1..p5 are zero-padded bit maps
    u64* ws  = (u64*)d_ws;
    u64* wp2 = ws;              // 9*2*128  = 2304
    u64* wp3 = wp2 + 2304;      // 9*2*256  = 4608
    u64* wp4 = wp3 + 4608;      // 9*4*256  = 9216
    u64* wp5 = wp4 + 9216;      // 9*4*512  = 18432
    u64* wp6 = wp5 + 18432;     // 9*8*512  = 36864
    u64* p1  = wp6 + 36864;     // 128*34*34*2 = 295936
    u64* p2  = p1 + 295936;     // 128*18*18*2 = 82944
    u64* p3  = p2 + 82944;      // 128*18*18*4 = 165888
    u64* p4  = p3 + 165888;     // 128*10*10*4 = 51200
    u64* p5  = p4 + 51200;      // 128*10*10*8 = 102400
    float* h6 = (float*)(p5 + 102400);  // 128*4*4*512 floats = 4 MB
    const int NPAD = 295936 + 82944 + 165888 + 51200 + 102400;  // 698368

    // zero padded maps (halos must be 0; interiors overwritten by producers)
    zero_kernel<<<1024, 256, 0, stream>>>(p1, NPAD);

    // pack binary weights (sign bits)
    pack_weights_kernel<<<(9*2*128*64)/256, 256, 0, stream>>>(w2, wp2, 128, 128);
    pack_weights_kernel<<<(9*2*256*64)/256, 256, 0, stream>>>(w3, wp3, 128, 256);
    pack_weights_kernel<<<(9*4*256*64)/256, 256, 0, stream>>>(w4, wp4, 256, 256);
    pack_weights_kernel<<<(9*4*512*64)/256, 256, 0, stream>>>(w5, wp5, 256, 512);
    pack_weights_kernel<<<(9*8*512*64)/256, 256, 0, stream>>>(w6, wp6, 512, 512);

    // conv1 + bn1 -> p1 (padded)
    conv1_pack_kernel<<<128*32*4, 128, 0, stream>>>(x, w1, b1, bn1s, bn1b, p1);

    // conv2 (pool) : 128*16*2 = 4096 waves
    bconv2_kernel<2,32,32,128,true, true ><<<1024, 256, 0, stream>>>(p1, wp2, bn2s, bn2b, p2, nullptr);
    // conv3        : 128*16*4 = 8192 waves
    bconv2_kernel<2,16,16,256,false,true ><<<2048, 256, 0, stream>>>(p2, wp3, bn3s, bn3b, p3, nullptr);
    // conv4 (pool) : 128*8*4 = 4096 waves
    bconv2_kernel<4,16,16,256,true, true ><<<1024, 256, 0, stream>>>(p3, wp4, bn4s, bn4b, p4, nullptr);
    // conv5        : 128*8*8 = 8192 waves
    bconv2_kernel<4,8,8,512,false,true ><<<2048, 256, 0, stream>>>(p4, wp5, bn5s, bn5b, p5, nullptr);
    // conv6 (pool, float out) : 128*4*8 = 4096 waves
    bconv2_kernel<8,8,8,512,true, false><<<1024, 256, 0, stream>>>(p5, wp6, bn6s, bn6b, nullptr, h6);

    // dense + softmax : 2048 rows, one wave each
    dense_softmax_kernel<<<2048*64/256, 256, 0, stream>>>(h6, dw, db, out);
}

// Round 4
// 359.449 us; speedup vs baseline: 1.4485x; 1.0482x over previous
//
#include <hip/hip_runtime.h>
#include <cstdint>

typedef unsigned long long u64;

// ---------------------------------------------------------------------------
// Zero a u64 region (padded bit-map halos must be 0; ws is poisoned 0xAA).
// ---------------------------------------------------------------------------
__global__ void zero_kernel(u64* __restrict__ p, int n) {
    int i = blockIdx.x * blockDim.x + threadIdx.x;
    int stride = gridDim.x * blockDim.x;
    for (; i < n; i += stride) p[i] = 0;
}

// ---------------------------------------------------------------------------
// Weight sign-packing, COMPLEMENTED: bit i of wp[(tap*Wi+cw)*Cout+oc] is
// !(w[tap][cw*64+i][oc] > 0).  Then #matches = popcll(act ^ wp) directly
// (pure xor+bcnt in the hot loop, no v_not).
// ---------------------------------------------------------------------------
__global__ void pack_weights_kernel(const float* __restrict__ w, u64* __restrict__ wp,
                                    int Cin, int Cout) {
    int tid = blockIdx.x * blockDim.x + threadIdx.x;
    int wid = tid >> 6;
    int lane = threadIdx.x & 63;
    int Wi = Cin >> 6;
    int total = 9 * Wi * Cout;
    if (wid >= total) return;
    int oc = wid % Cout;
    int tw = wid / Cout;          // tap*Wi + cw
    int tap = tw / Wi;
    int cw = tw % Wi;
    int ci = cw * 64 + lane;
    float v = w[((size_t)tap * Cin + ci) * Cout + oc];
    u64 mask = __ballot(!(v > 0.0f));
    if (lane == 0) wp[(size_t)tw * Cout + oc] = mask;
}

// ---------------------------------------------------------------------------
// conv1 (float, 3->128) + b1 + relu + bn1 -> sign bits, written into the
// PADDED 34x34x2-word p1 map. Weights in VGPRs, 8 px/thread sliding window.
// Double accumulation: sign decisions feed 5 binary layers; must be exact.
// ---------------------------------------------------------------------------
__global__ __launch_bounds__(128) void conv1_pack_kernel(
        const float* __restrict__ x, const float* __restrict__ w1,
        const float* __restrict__ b1, const float* __restrict__ s1,
        const float* __restrict__ bb1, u64* __restrict__ p1) {
    const int t = threadIdx.x;
    const int oc = t;
    const int bx = blockIdx.x;
    const int xseg = (bx & 3) << 3;    // 0,8,16,24
    const int y = (bx >> 2) & 31;
    const int b = bx >> 7;

    double wreg[27];
    #pragma unroll
    for (int k = 0; k < 27; k++) wreg[k] = (double)w1[k * 128 + oc];
    const double b1v = (double)b1[oc];
    // h = relu(acc+b1)*s + bb > 0  <=>  (bb>0) || acc > -bb/s - b1   (s>0)
    const double tneg = -(double)bb1[oc] / (double)s1[oc];
    const bool always = tneg < 0.0;
    const double thr = tneg - b1v;

    double acc[8];
    #pragma unroll
    for (int i = 0; i < 8; i++) acc[i] = 0.0;

    #pragma unroll
    for (int ky = 0; ky < 3; ky++) {
        int iy = y - 1 + ky;
        if (iy < 0 || iy > 31) continue;
        #pragma unroll
        for (int col = 0; col < 10; col++) {
            int ix = xseg - 1 + col;
            if (ix < 0 || ix > 31) continue;
            const float* xp = x + ((b * 32 + iy) * 32 + ix) * 3;
            #pragma unroll
            for (int c = 0; c < 3; c++) {
                double xv = (double)xp[c];
                #pragma unroll
                for (int kx = 0; kx < 3; kx++) {
                    int px = col - kx;          // output pixel this tap feeds
                    if (px >= 0 && px < 8)
                        acc[px] += xv * wreg[(ky * 3 + kx) * 3 + c];
                }
            }
        }
    }
    #pragma unroll
    for (int px = 0; px < 8; px++) {
        bool bit = always || (acc[px] > thr);
        u64 m = __ballot(bit);
        if ((t & 63) == 0)
            p1[((size_t)(b * 34 + y + 1) * 34 + xseg + px + 1) * 2 + (t >> 6)] = m;
    }
}

// ---------------------------------------------------------------------------
// Binary conv v3: zero-padded maps; weights streamed in (3 taps x CH<=4 words)
// register chunks via a NON-unrolled runtime loop -> no spills at WI=8.
// One wave = Wg pre-pool cols x 64 oc. XS column-split gives 8192 waves/layer.
// Padding handled by exact integer correction:
//   d = 2*m_total + 2*S_oob - 64*WI*(9 + n_oob),  S_oob from per-tap weight
// popcounts accumulated chunk-by-chunk.
// ---------------------------------------------------------------------------
template<int WI, int H, int W, int COUT, bool POOL, int XS, bool BITOUT>
__global__ __launch_bounds__(256, 4) void bconv3_kernel(
        const u64* __restrict__ in, const u64* __restrict__ wp,
        const float* __restrict__ bns, const float* __restrict__ bnb,
        u64* __restrict__ outb, float* __restrict__ outf) {
    constexpr int ROWS = POOL ? 2 : 1;       // pre-pool rows per wave
    constexpr int Ho   = POOL ? H / 2 : H;
    constexpr int Wo   = POOL ? W / 2 : W;
    constexpr int WoW  = COUT >> 6;
    constexpr int Hp   = H + 2, Wp = W + 2;
    constexpr int Wg   = W / XS;             // pre-pool cols per wave
    constexpr int Wog  = Wo / XS;            // output cols per wave
    constexpr int CH   = (WI < 4) ? WI : 4;  // weight words resident per chunk
    constexpr int NC   = WI / CH;            // chunks per tap-row

    const int lane = threadIdx.x & 63;
    int wid = (blockIdx.x * blockDim.x + threadIdx.x) >> 6;
    wid = __builtin_amdgcn_readfirstlane(wid);   // SGPR -> scalar a-loads
    const int wordo = wid % WoW;
    int t = wid / WoW;
    const int xg = t % XS; t /= XS;
    const int oy = t % Ho;
    const int b  = t / Ho;
    if (b >= 128) return;
    const int oc = wordo * 64 + lane;
    const int c0 = xg * Wg;                  // first pre-pool col (abs)
    const int base = POOL ? oy * 2 : oy;     // first pre-pool row (abs)

    int m[ROWS][Wg];
    #pragma unroll
    for (int r = 0; r < ROWS; r++)
        #pragma unroll
        for (int c = 0; c < Wg; c++) m[r][c] = 0;

    int S_top = 0, S_bot = 0, S_lef = 0, S_rig = 0;
    int C_tl = 0, C_tr = 0, C_bl = 0, C_br = 0;

    const u64* wbase = wp + oc;
    const u64* inb = in + (((size_t)b * Hp + base) * Wp + c0) * WI;

    #pragma unroll 1
    for (int kc = 0; kc < 3 * NC; kc++) {
        const int ky = kc / NC;
        const int ch = kc % NC;
        const int woff = ky * 3 * WI + ch * CH;
        u64 wk[3][CH];
        #pragma unroll
        for (int kx = 0; kx < 3; kx++)
            #pragma unroll
            for (int cw = 0; cw < CH; cw++)
                wk[kx][cw] = wbase[(size_t)(woff + kx * WI + cw) * COUT];

        // original-weight popcounts for this chunk (stored is complemented)
        int pg[3];
        #pragma unroll
        for (int kx = 0; kx < 3; kx++) {
            int s = 0;
            #pragma unroll
            for (int cw = 0; cw < CH; cw++) s += (int)__popcll(wk[kx][cw]);
            pg[kx] = 64 * CH - s;
        }
        S_lef += pg[0]; S_rig += pg[2];
        if (ky == 0) { S_top += pg[0] + pg[1] + pg[2]; C_tl += pg[0]; C_tr += pg[2]; }
        if (ky == 2) { S_bot += pg[0] + pg[1] + pg[2]; C_bl += pg[0]; C_br += pg[2]; }

        #pragma unroll
        for (int r = 0; r < ROWS; r++) {
            const u64* inrow = inb + (size_t)(r + ky) * Wp * WI + ch * CH;
            #pragma unroll
            for (int c = 0; c < Wg + 2; c++) {
                u64 av[CH];
                #pragma unroll
                for (int cw = 0; cw < CH; cw++) av[cw] = inrow[(size_t)c * WI + cw];
                #pragma unroll
                for (int kx = 0; kx < 3; kx++) {
                    const int col = c - kx;
                    if (col < 0 || col >= Wg) continue;
                    int acc = m[r][col];
                    #pragma unroll
                    for (int cw = 0; cw < CH; cw++)
                        acc += (int)__popcll(av[cw] ^ wk[kx][cw]);  // matches
                    m[r][col] = acc;
                }
            }
        }
    }

    // ---- epilogue: padding correction, relu+pool max, threshold ----
    const double sc = (double)bns[oc];
    const double bi = (double)bnb[oc];

    #pragma unroll
    for (int po = 0; po < Wog; po++) {
        int pmax = 0;                        // relu then max == max(0, d...)
        #pragma unroll
        for (int r = 0; r < ROWS; r++) {
            #pragma unroll
            for (int wx = 0; wx < (POOL ? 2 : 1); wx++) {
                const int lc = POOL ? po * 2 + wx : po;   // local pre-pool col
                const int pc = c0 + lc;                   // abs pre-pool col
                const int pr = base + r;                  // abs pre-pool row
                const int top = (pr == 0), bot = (pr == H - 1);
                const int lef = (pc == 0), rig = (pc == W - 1);
                int n_oob = 3 * (top + bot + lef + rig)
                          - (top & lef) - (top & rig) - (bot & lef) - (bot & rig);
                int S = top * S_top + bot * S_bot + lef * S_lef + rig * S_rig
                      - (top & lef) * C_tl - (top & rig) * C_tr
                      - (bot & lef) * C_bl - (bot & rig) * C_br;
                int d = 2 * m[r][lc] + 2 * S - 64 * WI * (9 + n_oob);
                pmax = d > pmax ? d : pmax;
            }
        }
        double h = (double)pmax * sc + bi;
        if constexpr (BITOUT) {
            u64 mask = __ballot(h > 0.0);
            if (lane == 0)
                outb[((size_t)(b * (Ho + 2) + oy + 1) * (Wo + 2) + xg * Wog + po + 1) * WoW + wordo] = mask;
        } else {
            outf[((size_t)(b * Ho + oy) * Wo + xg * Wog + po) * COUT + oc] = (float)h;
        }
    }
}

// ---------------------------------------------------------------------------
// Dense (512x10) + softmax. One wave per row (b,y,x). 2048 rows.
// ---------------------------------------------------------------------------
__global__ __launch_bounds__(256) void dense_softmax_kernel(
        const float* __restrict__ h6, const float* __restrict__ dw,
        const float* __restrict__ db, float* __restrict__ out) {
    int lane = threadIdx.x & 63;
    int r = (blockIdx.x * blockDim.x + threadIdx.x) >> 6;
    if (r >= 2048) return;
    const float* hr = h6 + (size_t)r * 512;
    float part[10];
    #pragma unroll
    for (int d = 0; d < 10; d++) part[d] = 0.f;
    #pragma unroll
    for (int k = 0; k < 8; k++) {
        int c = lane + 64 * k;
        float hv = hr[c];
        const float* dwr = dw + c * 10;
        #pragma unroll
        for (int d = 0; d < 10; d++) part[d] += hv * dwr[d];
    }
    #pragma unroll
    for (int off = 32; off >= 1; off >>= 1) {
        #pragma unroll
        for (int d = 0; d < 10; d++) part[d] += __shfl_down(part[d], off, 64);
    }
    if (lane == 0) {
        float logits[10];
        float mx = -1e30f;
        #pragma unroll
        for (int d = 0; d < 10; d++) { logits[d] = part[d] + db[d]; mx = fmaxf(mx, logits[d]); }
        float se = 0.f;
        #pragma unroll
        for (int d = 0; d < 10; d++) { logits[d] = expf(logits[d] - mx); se += logits[d]; }
        float inv = 1.f / se;
        #pragma unroll
        for (int d = 0; d < 10; d++) out[(size_t)r * 10 + d] = logits[d] * inv;
    }
}

// ---------------------------------------------------------------------------
extern "C" void kernel_launch(void* const* d_in, const int* in_sizes, int n_in,
                              void* d_out, int out_size, void* d_ws, size_t ws_size,
                              hipStream_t stream) {
    const float* x    = (const float*)d_in[0];
    const float* w1   = (const float*)d_in[1];
    const float* b1   = (const float*)d_in[2];
    const float* w2   = (const float*)d_in[3];
    const float* w3   = (const float*)d_in[4];
    const float* w4   = (const float*)d_in[5];
    const float* w5   = (const float*)d_in[6];
    const float* w6   = (const float*)d_in[7];
    const float* bn1s = (const float*)d_in[8];
    const float* bn1b = (const float*)d_in[9];
    const float* bn2s = (const float*)d_in[10];
    const float* bn2b = (const float*)d_in[11];
    const float* bn3s = (const float*)d_in[12];
    const float* bn3b = (const float*)d_in[13];
    const float* bn4s = (const float*)d_in[14];
    const float* bn4b = (const float*)d_in[15];
    const float* bn5s = (const float*)d_in[16];
    const float* bn5b = (const float*)d_in[17];
    const float* bn6s = (const float*)d_in[18];
    const float* bn6b = (const float*)d_in[19];
    const float* dw   = (const float*)d_in[20];
    const float* db   = (const float*)d_in[21];
    float* out = (float*)d_out;

    // workspace layout (u64 units); p1..p5 are zero-padded bit maps
    u64* ws  = (u64*)d_ws;
    u64* wp2 = ws;              // 9*2*128  = 2304
    u64* wp3 = wp2 + 2304;      // 9*2*256  = 4608
    u64* wp4 = wp3 + 4608;      // 9*4*256  = 9216
    u64* wp5 = wp4 + 9216;      // 9*4*512  = 18432
    u64* wp6 = wp5 + 18432;     // 9*8*512  = 36864
    u64* p1  = wp6 + 36864;     // 128*34*34*2 = 295936
    u64* p2  = p1 + 295936;     // 128*18*18*2 = 82944
    u64* p3  = p2 + 82944;      // 128*18*18*4 = 165888
    u64* p4  = p3 + 165888;     // 128*10*10*4 = 51200
    u64* p5  = p4 + 51200;      // 128*10*10*8 = 102400
    float* h6 = (float*)(p5 + 102400);  // 128*4*4*512 floats = 4 MB
    const int NPAD = 295936 + 82944 + 165888 + 51200 + 102400;  // 698368

    // zero padded maps (halos must be 0; interiors overwritten by producers)
    zero_kernel<<<1024, 256, 0, stream>>>(p1, NPAD);

    // pack binary weights (complemented sign bits)
    pack_weights_kernel<<<(9*2*128*64)/256, 256, 0, stream>>>(w2, wp2, 128, 128);
    pack_weights_kernel<<<(9*2*256*64)/256, 256, 0, stream>>>(w3, wp3, 128, 256);
    pack_weights_kernel<<<(9*4*256*64)/256, 256, 0, stream>>>(w4, wp4, 256, 256);
    pack_weights_kernel<<<(9*4*512*64)/256, 256, 0, stream>>>(w5, wp5, 256, 512);
    pack_weights_kernel<<<(9*8*512*64)/256, 256, 0, stream>>>(w6, wp6, 512, 512);

    // conv1 + bn1 -> p1 (padded)
    conv1_pack_kernel<<<128*32*4, 128, 0, stream>>>(x, w1, b1, bn1s, bn1b, p1);

    // each binary layer: exactly 8192 waves = 2048 blocks of 256
    bconv3_kernel<2,32,32,128,true, 2,true ><<<2048, 256, 0, stream>>>(p1, wp2, bn2s, bn2b, p2, nullptr);
    bconv3_kernel<2,16,16,256,false,1,true ><<<2048, 256, 0, stream>>>(p2, wp3, bn3s, bn3b, p3, nullptr);
    bconv3_kernel<4,16,16,256,true, 2,true ><<<2048, 256, 0, stream>>>(p3, wp4, bn4s, bn4b, p4, nullptr);
    bconv3_kernel<4,8,8,512,false,1,true ><<<2048, 256, 0, stream>>>(p4, wp5, bn5s, bn5b, p5, nullptr);
    bconv3_kernel<8,8,8,512,true, 2,false><<<2048, 256, 0, stream>>>(p5, wp6, bn6s, bn6b, nullptr, h6);

    // dense + softmax : 2048 rows, one wave each
    dense_softmax_kernel<<<2048*64/256, 256, 0, stream>>>(h6, dw, db, out);
}